// Round 1
// 14394.502 us; speedup vs baseline: 1.2940x; 1.2940x over previous
//
#include <hip/hip_runtime.h>
#include <hip/hip_bf16.h>
#include <math.h>

// LSTM L=2, T=512, B=64, H=1024 — fp32 in/out.
// Persistent kernel: weights bf16 in registers, 256 blocks x 1024 thr,
// manual grid barrier per pipeline step (layer0 at t=p, layer1 at t=p-1).
//
// R(this): remove ALL cache-maintenance fences (buffer_wbl2/buffer_inv from
// __threadfence was ~30us/step of serialized per-block L2 walks). Cross-block
// h state now moves through relaxed AGENT-scope atomics (sc1: bypass the
// non-coherent per-XCD L2, coherent at memory side). Barrier = relaxed agent
// atomicAdd + relaxed spin; ordering via __syncthreads' vmcnt(0) drain.
// xbf staging removed: layer0 reads immutable x fp32 directly (L2-cached)
// and converts in-register.
//
// d_out = concat(hs [T,B,H], output_hs [L,B,H], output_cs [L,B,H]) fp32,
// output_cs == output_hs (reference bug replicated). c state in registers.

#define Hh 1024
#define Bb 64
#define Tt 512
#define BH (Bb*Hh)      // 65536
#define G4 (4*Hh)       // 4096

typedef __bf16 v8bf __attribute__((ext_vector_type(8)));
typedef float  v4f  __attribute__((ext_vector_type(4)));
typedef int    v4i  __attribute__((ext_vector_type(4)));
typedef unsigned long long u64;
typedef __hip_bfloat16 bf16;

__device__ __forceinline__ bf16 f2bf(float v){ return __float2bfloat16(v); }

__device__ __forceinline__ v8bf cvt8(const float* p) {
    v4f a = *(const v4f*)p;
    v4f b = *(const v4f*)(p + 4);
    v8bf r;
    #pragma unroll
    for (int i = 0; i < 4; ++i) {
        r[i]   = __builtin_bit_cast(__bf16, f2bf(a[i]));
        r[i+4] = __builtin_bit_cast(__bf16, f2bf(b[i]));
    }
    return r;
}

// 16B coherent (agent-scope) load of 8 bf16 from the non-L2-cached h buffer.
// Relaxed atomic 8B loads compile to global_load_dwordx2 ... sc1.
__device__ __forceinline__ v8bf ld8bf_agent(const bf16* p) {
    const u64* q = (const u64*)p;
    u64 a = __hip_atomic_load(q,     __ATOMIC_RELAXED, __HIP_MEMORY_SCOPE_AGENT);
    u64 b = __hip_atomic_load(q + 1, __ATOMIC_RELAXED, __HIP_MEMORY_SCOPE_AGENT);
    union { u64 v[2]; v8bf r; } u;
    u.v[0] = a; u.v[1] = b;
    return u.r;
}

__device__ __forceinline__ float fast_sigmoid(float x) {
    x = fminf(fmaxf(x, -30.f), 30.f);
    return 1.f / (1.f + __expf(-x));
}
__device__ __forceinline__ float fast_tanh(float x) {
    x = fminf(fmaxf(x, -15.f), 15.f);
    float e = __expf(2.f * x);
    return (e - 1.f) / (e + 1.f);
}

// ws: bar (256 B) | hout[2 layers][2 parity][BH] bf16
__global__ void init_ws(const float* __restrict__ h0,
                        bf16* __restrict__ hout, unsigned int* __restrict__ bar) {
    int i = blockIdx.x * blockDim.x + threadIdx.x;   // 256x256 = BH exactly
    if (i == 0) *bar = 0u;
    hout[(0*2 + 1)*BH + i] = f2bf(h0[i]);       // layer0 reads parity (p-1)&1=1 at p=0
    hout[(1*2 + 0)*BH + i] = f2bf(h0[BH + i]);  // layer1 reads parity 0 at p=1
}

// Block b: layer = b>>7, jslice = b&127 (8 j-cols, 32 gate-cols).
// 16 waves = ks(2: Wi/x vs Wh/h) x kh(2: K-half of 512) x rt(4: 16-row tile).
__global__ __launch_bounds__(1024, 4)
void lstm_persist(const float* __restrict__ x,
                  const float* __restrict__ wi, const float* __restrict__ bi,
                  const float* __restrict__ wh, const float* __restrict__ bh,
                  const float* __restrict__ c0,
                  bf16* __restrict__ hout,
                  float* __restrict__ out, unsigned int* __restrict__ bar)
{
    const int layer  = blockIdx.x >> 7;
    const int jslice = blockIdx.x & 127;
    const int jbase  = jslice * 8;

    const int tid  = threadIdx.x;
    const int lane = tid & 63;
    const int w    = tid >> 6;          // 0..15
    const int ks   = w >> 3;            // 0: x-half(Wi), 1: h-half(Wh)
    const int kh   = (w >> 2) & 1;      // K half (512 each)
    const int rt   = w & 3;             // row tile
    const int s    = w >> 2;            // partial index 0..3
    const int quad = lane >> 4;
    const int l15  = lane & 15;

    // ---- load weights into registers (bf16 fragments) ----
    const float* W = (ks ? wh : wi) + (size_t)layer * G4 * Hh;
    v8bf Breg[16][2];
    #pragma unroll
    for (int ct = 0; ct < 2; ++ct) {
        const int n    = ct*16 + l15;
        const int grow = (n >> 3)*Hh + jbase + (n & 7);
        const float* wp = W + (size_t)grow * Hh + kh*512 + quad*8;
        #pragma unroll
        for (int kk = 0; kk < 16; ++kk)
            Breg[kk][ct] = cvt8(wp + kk*32);
    }

    // A-fragment offset within the chosen activation buffer (elements)
    const int arow = rt*16 + l15;
    const size_t aoff = (size_t)arow * Hh + kh*512 + quad*8;

    // ---- epilogue per-thread constants (tid < 256: 2 cells each) ----
    const int eb  = tid >> 2;           // batch row 0..63
    const int ejp = tid & 3;            // j pair within slice (covers ej=2*ejp, 2*ejp+1)
    float bsum[4][2];
    float c_reg[2] = {0.f, 0.f};
    if (tid < 256) {
        #pragma unroll
        for (int gi = 0; gi < 4; ++gi) {
            #pragma unroll
            for (int u = 0; u < 2; ++u) {
                int bo = layer*G4 + gi*Hh + jbase + 2*ejp + u;
                bsum[gi][u] = bi[bo] + bh[bo];
            }
        }
        #pragma unroll
        for (int u = 0; u < 2; ++u)
            c_reg[u] = c0[(size_t)layer*BH + eb*Hh + jbase + 2*ejp + u];
    }

    __shared__ float part[4][64][36];   // padded

    for (int p = 0; p <= Tt; ++p) {
        const int t = p - layer;
        const bool act = (t >= 0) & (t < Tt);

        if (act) {
            v4f acc0 = {0.f,0.f,0.f,0.f}, acc1 = {0.f,0.f,0.f,0.f};
            if (ks == 0 && layer == 0) {
                // immutable input: normal cached fp32 loads, convert in-register
                const float* ap = x + (size_t)t*BH + aoff;
                #pragma unroll
                for (int kk = 0; kk < 16; ++kk) {
                    v8bf af = cvt8(ap + kk*32);
                    acc0 = __builtin_amdgcn_mfma_f32_16x16x32_bf16(af, Breg[kk][0], acc0, 0,0,0);
                    acc1 = __builtin_amdgcn_mfma_f32_16x16x32_bf16(af, Breg[kk][1], acc1, 0,0,0);
                }
            } else {
                // cross-block h state: coherent (sc1) loads
                const int srcbuf = (ks == 0) ? ((p-1) & 1)               // layer1 input: hout[0][(p-1)&1]
                                             : (layer*2 + ((p-1) & 1));  // own prev h
                const bf16* ap = hout + (size_t)srcbuf*BH + aoff;
                #pragma unroll
                for (int kk = 0; kk < 16; ++kk) {
                    v8bf af = ld8bf_agent(ap + kk*32);
                    acc0 = __builtin_amdgcn_mfma_f32_16x16x32_bf16(af, Breg[kk][0], acc0, 0,0,0);
                    acc1 = __builtin_amdgcn_mfma_f32_16x16x32_bf16(af, Breg[kk][1], acc1, 0,0,0);
                }
            }
            // C/D layout: col = lane&15, row = quad*4 + r
            #pragma unroll
            for (int r = 0; r < 4; ++r) {
                part[s][rt*16 + quad*4 + r][l15]      = acc0[r];
                part[s][rt*16 + quad*4 + r][16 + l15] = acc1[r];
            }
        }
        __syncthreads();

        if (tid < 256 && act) {
            float g[4][2];
            #pragma unroll
            for (int gi = 0; gi < 4; ++gi) {
                int c = gi*8 + 2*ejp;
                g[gi][0] = part[0][eb][c]   + part[1][eb][c]
                         + part[2][eb][c]   + part[3][eb][c]   + bsum[gi][0];
                g[gi][1] = part[0][eb][c+1] + part[1][eb][c+1]
                         + part[2][eb][c+1] + part[3][eb][c+1] + bsum[gi][1];
            }
            float hv[2];
            #pragma unroll
            for (int u = 0; u < 2; ++u) {
                float ig = fast_sigmoid(g[0][u]);
                float fg = fast_sigmoid(g[1][u]);
                float gv = fast_tanh(g[2][u]);
                float og = fast_sigmoid(g[3][u]);
                c_reg[u] = c_reg[u]*fg + ig*gv;
                hv[u] = og * fast_tanh(c_reg[u]);
            }

            const int idx = eb*Hh + jbase + 2*ejp;   // even -> 4B/8B aligned
            unsigned int hp =
                  (unsigned int)__builtin_bit_cast(unsigned short, f2bf(hv[0]))
                | ((unsigned int)__builtin_bit_cast(unsigned short, f2bf(hv[1])) << 16);
            // coherent store (sc1): visible agent-wide once vmcnt drains
            __hip_atomic_store((unsigned int*)(hout + (size_t)(layer*2 + (p & 1))*BH + idx),
                               hp, __ATOMIC_RELAXED, __HIP_MEMORY_SCOPE_AGENT);
            if (layer == 1) {
                float2 o; o.x = hv[0]; o.y = hv[1];
                *(float2*)(out + (size_t)t*BH + idx) = o;
            }
            if (t == Tt-1) {
                float2 o; o.x = hv[0]; o.y = hv[1];
                *(float2*)(out + (size_t)Tt*BH + (size_t)layer*BH + idx)       = o;
                *(float2*)(out + (size_t)Tt*BH + (size_t)(2 + layer)*BH + idx) = o;
            }
        }

        if (p < Tt) {   // grid barrier (skip after final step)
            // __syncthreads drains vmcnt(0) per wave before s_barrier, so every
            // block's sc1 h-stores are at the coherence point before the arrive.
            __syncthreads();
            if (tid == 0) {
                __hip_atomic_fetch_add(bar, 1u, __ATOMIC_RELAXED, __HIP_MEMORY_SCOPE_AGENT);
                const unsigned int target = (unsigned int)(p + 1) * 256u;
                while (__hip_atomic_load(bar, __ATOMIC_RELAXED, __HIP_MEMORY_SCOPE_AGENT) < target)
                    __builtin_amdgcn_s_sleep(2);
            }
            __syncthreads();
        }
    }
}

extern "C" void kernel_launch(void* const* d_in, const int* in_sizes, int n_in,
                              void* d_out, int out_size, void* d_ws, size_t ws_size,
                              hipStream_t stream) {
    const float* x  = (const float*)d_in[0];
    const float* h0 = (const float*)d_in[1];
    const float* c0 = (const float*)d_in[2];
    const float* wi = (const float*)d_in[3];
    const float* bi = (const float*)d_in[4];
    const float* wh = (const float*)d_in[5];
    const float* bh = (const float*)d_in[6];
    float* out = (float*)d_out;

    // ws: bar 256 B | hout 4*BH bf16 (512 KB)
    char* ws = (char*)d_ws;
    unsigned int* bar = (unsigned int*)ws;
    bf16* hout = (bf16*)(ws + 256);

    init_ws<<<256, 256, 0, stream>>>(h0, hout, bar);
    lstm_persist<<<256, 1024, 0, stream>>>(x, wi, bi, wh, bh, c0,
                                           hout, out, bar);
}

// Round 3
// 12497.817 us; speedup vs baseline: 1.4904x; 1.1518x over previous
//
#include <hip/hip_runtime.h>
#include <hip/hip_bf16.h>
#include <math.h>

// LSTM L=2, T=512, B=64, H=1024 — fp32 in/out.
// Persistent kernel: weights bf16 in registers (acc file), 256 blocks x 1024
// thr, manual grid barrier per pipeline step (layer0 t=p, layer1 t=p-1).
//
// R3 (= R2 hardened): (a) h-GEMM A-loads are inline-asm global_load_dwordx4
// sc0 sc1 (memory-side coherent, bypass L1/L2), software-pipelined depth-8
// through TWO named 4-fragment buffers (32 VGPR peak, constant-indexed),
// counted s_waitcnt vmcnt(4/4/4/0) + sched_barrier(0) fences around each
// MFMA group (guide rule #18). R2's af[16] (64 VGPR) risked spilled asm
// destinations = garbage/crash. (b) grid barrier distributed over 16
// cacheline-separated counters (16 arrivals each/step); wave-0 lanes 0..15
// poll in parallel, ballot-reduced. Ordering: __syncthreads drains sc1
// stores pre-arrive; __syncthreads after poll fences post-barrier loads.
//
// d_out = concat(hs [T,B,H], output_hs [L,B,H], output_cs [L,B,H]) fp32,
// output_cs == output_hs (reference bug replicated). c state in registers.

#define Hh 1024
#define Bb 64
#define Tt 512
#define BH (Bb*Hh)      // 65536
#define G4 (4*Hh)       // 4096

typedef __bf16 v8bf __attribute__((ext_vector_type(8)));
typedef float  v4f  __attribute__((ext_vector_type(4)));
typedef unsigned long long u64;
typedef __hip_bfloat16 bf16;

__device__ __forceinline__ bf16 f2bf(float v){ return __float2bfloat16(v); }

__device__ __forceinline__ v8bf cvt8(const float* p) {
    v4f a = *(const v4f*)p;
    v4f b = *(const v4f*)(p + 4);
    v8bf r;
    #pragma unroll
    for (int i = 0; i < 4; ++i) {
        r[i]   = __builtin_bit_cast(__bf16, f2bf(a[i]));
        r[i+4] = __builtin_bit_cast(__bf16, f2bf(b[i]));
    }
    return r;
}

__device__ __forceinline__ float fast_sigmoid(float x) {
    x = fminf(fmaxf(x, -30.f), 30.f);
    return 1.f / (1.f + __expf(-x));
}
__device__ __forceinline__ float fast_tanh(float x) {
    x = fminf(fmaxf(x, -15.f), 15.f);
    float e = __expf(2.f * x);
    return (e - 1.f) / (e + 1.f);
}

// 4 coherent 16B loads into a named buffer, no wait. base is a constant.
#define ISS4(buf, base) do {                                                   \
    asm volatile("global_load_dwordx4 %0, %1, off sc0 sc1"                     \
                 : "=v"(buf[0]) : "v"(ap + (base+0)*32));                      \
    asm volatile("global_load_dwordx4 %0, %1, off sc0 sc1"                     \
                 : "=v"(buf[1]) : "v"(ap + (base+1)*32));                      \
    asm volatile("global_load_dwordx4 %0, %1, off sc0 sc1"                     \
                 : "=v"(buf[2]) : "v"(ap + (base+2)*32));                      \
    asm volatile("global_load_dwordx4 %0, %1, off sc0 sc1"                     \
                 : "=v"(buf[3]) : "v"(ap + (base+3)*32));                      \
} while (0)

#define MFMA4(buf, base) do {                                                  \
    _Pragma("unroll")                                                          \
    for (int k = 0; k < 4; ++k) {                                              \
        acc0 = __builtin_amdgcn_mfma_f32_16x16x32_bf16(buf[k], Breg[(base)+k][0], acc0, 0,0,0); \
        acc1 = __builtin_amdgcn_mfma_f32_16x16x32_bf16(buf[k], Breg[(base)+k][1], acc1, 0,0,0); \
    }                                                                          \
} while (0)

// ws: bar[16] counters, 64B apart (1 KB) | hout[2 layers][2 parity][BH] bf16
__global__ void init_ws(const float* __restrict__ h0,
                        bf16* __restrict__ hout, unsigned int* __restrict__ bar) {
    int i = blockIdx.x * blockDim.x + threadIdx.x;   // 256x256 = BH exactly
    if (i < 256) bar[i] = 0u;
    hout[(0*2 + 1)*BH + i] = f2bf(h0[i]);       // layer0 reads parity (p-1)&1=1 at p=0
    hout[(1*2 + 0)*BH + i] = f2bf(h0[BH + i]);  // layer1 reads parity 0 at p=1
}

// Block b: layer = b>>7, jslice = b&127 (8 j-cols, 32 gate-cols).
// 16 waves = ks(2: Wi/x vs Wh/h) x kh(2: K-half of 512) x rt(4: 16-row tile).
__global__ __launch_bounds__(1024, 4)
void lstm_persist(const float* __restrict__ x,
                  const float* __restrict__ wi, const float* __restrict__ bi,
                  const float* __restrict__ wh, const float* __restrict__ bh,
                  const float* __restrict__ c0,
                  bf16* __restrict__ hout,
                  float* __restrict__ out, unsigned int* __restrict__ bar)
{
    const int layer  = blockIdx.x >> 7;
    const int jslice = blockIdx.x & 127;
    const int jbase  = jslice * 8;

    const int tid  = threadIdx.x;
    const int lane = tid & 63;
    const int w    = tid >> 6;          // 0..15
    const int ks   = w >> 3;            // 0: x-half(Wi), 1: h-half(Wh)
    const int kh   = (w >> 2) & 1;      // K half (512 each)
    const int rt   = w & 3;             // row tile
    const int s    = w >> 2;            // partial index 0..3
    const int quad = lane >> 4;
    const int l15  = lane & 15;

    // ---- load weights into registers (bf16 fragments; land in acc file) ----
    const float* W = (ks ? wh : wi) + (size_t)layer * G4 * Hh;
    v8bf Breg[16][2];
    #pragma unroll
    for (int ct = 0; ct < 2; ++ct) {
        const int n    = ct*16 + l15;
        const int grow = (n >> 3)*Hh + jbase + (n & 7);
        const float* wp = W + (size_t)grow * Hh + kh*512 + quad*8;
        #pragma unroll
        for (int kk = 0; kk < 16; ++kk)
            Breg[kk][ct] = cvt8(wp + kk*32);
    }

    // A-fragment offset within the chosen activation buffer (elements)
    const int arow = rt*16 + l15;
    const size_t aoff = (size_t)arow * Hh + kh*512 + quad*8;

    // ---- epilogue per-thread constants (tid < 256: 2 cells each) ----
    const int eb  = tid >> 2;           // batch row 0..63
    const int ejp = tid & 3;            // j pair within slice
    float bsum[4][2];
    float c_reg[2] = {0.f, 0.f};
    if (tid < 256) {
        #pragma unroll
        for (int gi = 0; gi < 4; ++gi) {
            #pragma unroll
            for (int u = 0; u < 2; ++u) {
                int bo = layer*G4 + gi*Hh + jbase + 2*ejp + u;
                bsum[gi][u] = bi[bo] + bh[bo];
            }
        }
        #pragma unroll
        for (int u = 0; u < 2; ++u)
            c_reg[u] = c0[(size_t)layer*BH + eb*Hh + jbase + 2*ejp + u];
    }

    __shared__ float part[4][64][36];   // padded

    for (int p = 0; p <= Tt; ++p) {
        const int t = p - layer;
        const bool act = (t >= 0) & (t < Tt);

        if (act) {
            v4f acc0 = {0.f,0.f,0.f,0.f}, acc1 = {0.f,0.f,0.f,0.f};
            if (ks == 0 && layer == 0) {
                // immutable input: normal cached fp32 loads, convert in-register
                const float* ap = x + (size_t)t*BH + aoff;
                #pragma unroll
                for (int kk = 0; kk < 16; ++kk) {
                    v8bf af = cvt8(ap + kk*32);
                    acc0 = __builtin_amdgcn_mfma_f32_16x16x32_bf16(af, Breg[kk][0], acc0, 0,0,0);
                    acc1 = __builtin_amdgcn_mfma_f32_16x16x32_bf16(af, Breg[kk][1], acc1, 0,0,0);
                }
            } else {
                // cross-block h state: coherent sc0+sc1 loads, depth-8 pipeline
                const int srcbuf = (ks == 0) ? ((p-1) & 1)               // layer1 in: hout[0][(p-1)&1]
                                             : (layer*2 + ((p-1) & 1));  // own prev h
                const bf16* ap = hout + (size_t)srcbuf*BH + aoff;
                v8bf afA[4], afB[4];
                ISS4(afA, 0);                        // 4 outstanding
                ISS4(afB, 4);                        // 8 outstanding
                asm volatile("s_waitcnt vmcnt(4)");  // afA landed
                __builtin_amdgcn_sched_barrier(0);
                MFMA4(afA, 0);
                __builtin_amdgcn_sched_barrier(0);
                ISS4(afA, 8);                        // 8 outstanding
                asm volatile("s_waitcnt vmcnt(4)");  // afB landed
                __builtin_amdgcn_sched_barrier(0);
                MFMA4(afB, 4);
                __builtin_amdgcn_sched_barrier(0);
                ISS4(afB, 12);                       // 8 outstanding
                asm volatile("s_waitcnt vmcnt(4)");  // afA(8..11) landed
                __builtin_amdgcn_sched_barrier(0);
                MFMA4(afA, 8);
                __builtin_amdgcn_sched_barrier(0);
                asm volatile("s_waitcnt vmcnt(0)");  // afB(12..15) landed
                __builtin_amdgcn_sched_barrier(0);
                MFMA4(afB, 12);
            }
            // C/D layout: col = lane&15, row = quad*4 + r
            #pragma unroll
            for (int r = 0; r < 4; ++r) {
                part[s][rt*16 + quad*4 + r][l15]      = acc0[r];
                part[s][rt*16 + quad*4 + r][16 + l15] = acc1[r];
            }
        }
        __syncthreads();

        if (tid < 256 && act) {
            float g[4][2];
            #pragma unroll
            for (int gi = 0; gi < 4; ++gi) {
                int c = gi*8 + 2*ejp;
                g[gi][0] = part[0][eb][c]   + part[1][eb][c]
                         + part[2][eb][c]   + part[3][eb][c]   + bsum[gi][0];
                g[gi][1] = part[0][eb][c+1] + part[1][eb][c+1]
                         + part[2][eb][c+1] + part[3][eb][c+1] + bsum[gi][1];
            }
            float hv[2];
            #pragma unroll
            for (int u = 0; u < 2; ++u) {
                float ig = fast_sigmoid(g[0][u]);
                float fg = fast_sigmoid(g[1][u]);
                float gv = fast_tanh(g[2][u]);
                float og = fast_sigmoid(g[3][u]);
                c_reg[u] = c_reg[u]*fg + ig*gv;
                hv[u] = og * fast_tanh(c_reg[u]);
            }

            const int idx = eb*Hh + jbase + 2*ejp;   // even -> 4B aligned pair
            unsigned int hp =
                  (unsigned int)__builtin_bit_cast(unsigned short, f2bf(hv[0]))
                | ((unsigned int)__builtin_bit_cast(unsigned short, f2bf(hv[1])) << 16);
            // coherent store (sc1): at coherence point once vmcnt drains
            __hip_atomic_store((unsigned int*)(hout + (size_t)(layer*2 + (p & 1))*BH + idx),
                               hp, __ATOMIC_RELAXED, __HIP_MEMORY_SCOPE_AGENT);
            if (layer == 1) {
                float2 o; o.x = hv[0]; o.y = hv[1];
                *(float2*)(out + (size_t)t*BH + idx) = o;
            }
            if (t == Tt-1) {
                float2 o; o.x = hv[0]; o.y = hv[1];
                *(float2*)(out + (size_t)Tt*BH + (size_t)layer*BH + idx)       = o;
                *(float2*)(out + (size_t)Tt*BH + (size_t)(2 + layer)*BH + idx) = o;
            }
        }

        if (p < Tt) {   // grid barrier (skip after final step)
            // __syncthreads drains vmcnt(0) per wave before s_barrier, so every
            // block's sc1 h-stores are at the coherence point before the arrive.
            __syncthreads();
            if (w == 0) {
                if (lane == 0)
                    __hip_atomic_fetch_add(bar + (blockIdx.x & 15)*16, 1u,
                                           __ATOMIC_RELAXED, __HIP_MEMORY_SCOPE_AGENT);
                const unsigned int tgt = (unsigned int)(p + 1) * 16u;
                bool done = (lane >= 16);
                while (!__all(done)) {
                    if (!done)
                        done = (__hip_atomic_load(bar + lane*16, __ATOMIC_RELAXED,
                                                  __HIP_MEMORY_SCOPE_AGENT) >= tgt);
                    if (!__all(done))
                        __builtin_amdgcn_s_sleep(2);
                }
            }
            __syncthreads();
        }
    }
}

extern "C" void kernel_launch(void* const* d_in, const int* in_sizes, int n_in,
                              void* d_out, int out_size, void* d_ws, size_t ws_size,
                              hipStream_t stream) {
    const float* x  = (const float*)d_in[0];
    const float* h0 = (const float*)d_in[1];
    const float* c0 = (const float*)d_in[2];
    const float* wi = (const float*)d_in[3];
    const float* bi = (const float*)d_in[4];
    const float* wh = (const float*)d_in[5];
    const float* bh = (const float*)d_in[6];
    float* out = (float*)d_out;

    // ws: bar 1 KB (16 counters, 64B apart) | hout 4*BH bf16 (512 KB)
    char* ws = (char*)d_ws;
    unsigned int* bar = (unsigned int*)ws;
    bf16* hout = (bf16*)(ws + 1024);

    init_ws<<<256, 256, 0, stream>>>(h0, hout, bar);
    lstm_persist<<<256, 1024, 0, stream>>>(x, wi, bi, wh, bh, c0,
                                           hout, out, bar);
}